// Round 4
// baseline (243.891 us; speedup 1.0000x reference)
//
#include <hip/hip_runtime.h>
#include <hip/hip_bf16.h>

// B,N,D,H = 4,2048,512,8 (DK=64). fp32 I/O; bf16 intermediates in ws.
// attn v7: 1024 thr = 16 waves = 4 waves/SIMD (v6 was 2). Wave (ns,ms,hs):
// ns owns 16 n-rows, ms a 16-m half, hs a 4-head group. Heads-softmax
// needs the full 8-head sum -> wave pairs exchange per-(n,m) partial
// exp-sums via 16KB LDS (Sx). Work/CU constant, parallelism 2x.
// Counted-vmcnt pipeline (3 barriers/chunk, never vmcnt(0) in steady state).
#define B_  4
#define N_  2048
#define D_  512
#define H_  8

typedef unsigned short u16;
typedef __attribute__((ext_vector_type(8))) unsigned short ushort8;
typedef __attribute__((ext_vector_type(4))) unsigned short us4;
typedef __attribute__((ext_vector_type(8))) short short8;
typedef __attribute__((ext_vector_type(4))) float float4v;

__device__ __forceinline__ float bf2f(u16 u) {
    union { unsigned int i; float f; } v;
    v.i = ((unsigned int)u) << 16;
    return v.f;
}
__device__ __forceinline__ u16 f2bf(float f) {          // RNE
    union { float f; unsigned int i; } v;
    v.f = f;
    unsigned int r = v.i + 0x7FFFu + ((v.i >> 16) & 1u);
    return (u16)(r >> 16);
}
__device__ __forceinline__ u16 f2bf_fast(float f) {     // round-half-up
    union { float f; unsigned int i; } v;
    v.f = f;
    return (u16)((v.i + 0x8000u) >> 16);
}

// async global->LDS, 16B/lane, dest = wave-uniform base + lane*16 (m104 rule)
__device__ __forceinline__ void gload_lds16(const void* g, void* l) {
    __builtin_amdgcn_global_load_lds(
        (const __attribute__((address_space(1))) unsigned int*)g,
        (__attribute__((address_space(3))) unsigned int*)l, 16, 0, 0);
}

#define WAIT_VM(N) do { \
    asm volatile("s_waitcnt vmcnt(" #N ")" ::: "memory"); \
    __builtin_amdgcn_sched_barrier(0); } while (0)
#define WAIT_LGKM0 do { \
    asm volatile("s_waitcnt lgkmcnt(0)" ::: "memory"); \
    __builtin_amdgcn_sched_barrier(0); } while (0)
#define BARRIER do { \
    __builtin_amdgcn_s_barrier(); \
    __builtin_amdgcn_sched_barrier(0); } while (0)

// ---------------------------------------------------------------------------
// wconv: Wq,Wo fp32 -> bf16, out = [Wqb | Wob]. grid (128, 2) x 256.
// (Path B only; Path A uses fused cvt4.)
// ---------------------------------------------------------------------------
__global__ __launch_bounds__(256) void wconv(
    const float* __restrict__ Wq, const float* __restrict__ Wo,
    u16* __restrict__ out)
{
    const int idx = (blockIdx.x * 256 + threadIdx.x) * 8;
    const float* src = blockIdx.y ? Wo : Wq;
    u16* dst = out + (size_t)blockIdx.y * (D_ * D_) + idx;
    float4v a = *(const float4v*)(src + idx);
    float4v b = *(const float4v*)(src + idx + 4);
    ushort8 o;
    #pragma unroll
    for (int j = 0; j < 4; ++j) { o[j] = f2bf(a[j]); o[j + 4] = f2bf(b[j]); }
    *(ushort8*)dst = o;
}

// ---------------------------------------------------------------------------
// cvt4: Q,K,V fp32 -> bf16 slabs, + Wq/Wo -> Wb fused (y==3 blocks).
// grid (NBD/2048, 4) x 256.
// ---------------------------------------------------------------------------
__global__ __launch_bounds__(256) void cvt4(
    const float* __restrict__ Q, const float* __restrict__ K,
    const float* __restrict__ V, const float* __restrict__ Wq,
    const float* __restrict__ Wo, u16* __restrict__ out,
    u16* __restrict__ wb)
{
    const int y = blockIdx.y;
    if (y == 3) {                      // weight conversion: 2*D*D elems
        if (blockIdx.x >= 256) return; // 256 blocks * 2048 = 524,288
        const int idx = (blockIdx.x * 256 + threadIdx.x) * 8;
        const bool hi = idx >= D_ * D_;     // no straddle: 2048 | D*D
        const float* src = hi ? Wo : Wq;
        const int off = hi ? idx - D_ * D_ : idx;
        float4v a = *(const float4v*)(src + off);
        float4v b = *(const float4v*)(src + off + 4);
        ushort8 o;
        #pragma unroll
        for (int j = 0; j < 4; ++j) { o[j] = f2bf(a[j]); o[j + 4] = f2bf(b[j]); }
        *(ushort8*)(wb + idx) = o;
        return;
    }
    const size_t NBD = (size_t)B_ * N_ * D_;
    const float* src = (y == 0) ? Q : ((y == 1) ? K : V);
    u16* dst = out + (size_t)y * NBD;
    size_t idx = ((size_t)blockIdx.x * 256 + threadIdx.x) * 8;
    float4v a = *(const float4v*)(src + idx);
    float4v b = *(const float4v*)(src + idx + 4);
    ushort8 o;
    #pragma unroll
    for (int j = 0; j < 4; ++j) { o[j] = f2bf(a[j]); o[j + 4] = f2bf(b[j]); }
    *(ushort8*)(dst + idx) = o;
}

// ---------------------------------------------------------------------------
// MFMA GEMM: C[M,512] = X @ W^T + bias.  1D grid, XCD swizzle: the 4 e-tiles
// of one (z,m) X-panel land on one XCD (flat&7 selects (z,m) low bits).
// INK: 0 = X fp32 (VALU cvt), 1 = X bf16 (gload), 2 = X0+X1 bf16 partials.
// WB16: W bf16 via gload. OUTB16: C bf16 (z==2 -> transposed Vpt[b][e][n]).
// 128x128 tile, 4 waves x 4x4 MFMA 16x16x32, BK=32.
// ---------------------------------------------------------------------------
template <int INK, bool WB16, bool OUTB16, int NZ>
__global__ __launch_bounds__(256) void proj_mfma(
    const void* __restrict__ X0v, const void* __restrict__ X1v,
    const void* __restrict__ X2v, const void* __restrict__ Wv,
    const float* __restrict__ bias, void* __restrict__ C0v, int M)
{
    __shared__ u16 As[128][32];
    __shared__ u16 Bs[128][32];

    const int t = threadIdx.x;
    // swizzle decode: flat = xcd + 8*(e + 4*g), zm = xcd + 8*g
    const int flat = blockIdx.x;
    const int xcd = flat & 7, rr = flat >> 3;
    const int eb = rr & 3, g = rr >> 2;
    const int zm = xcd + 8 * g;          // 0 .. 64*NZ-1
    const int z  = zm >> 6;
    const int e0 = eb * 128;
    const int m0 = (zm & 63) * 128;

    const void* Xv = (z == 0) ? X0v : ((z == 1) ? X1v : X2v);
    const int w = t >> 6, l = t & 63;
    const int lane16 = l & 15, quad = l >> 4;
    const int wr = (w >> 1) * 64;
    const int wc = (w & 1) * 64;

    float4v acc[4][4];
    #pragma unroll
    for (int i = 0; i < 4; ++i)
        #pragma unroll
        for (int j = 0; j < 4; ++j)
            acc[i][j] = (float4v){0.f, 0.f, 0.f, 0.f};

    for (int k0 = 0; k0 < 512; k0 += 32) {
        __syncthreads();

        // ---- stage A tile ----
        if (INK == 1) {
            const u16* X = (const u16*)Xv;
            #pragma unroll
            for (int i = 0; i < 2; ++i) {
                int r0 = w * 32 + i * 16;
                gload_lds16(X + (size_t)(m0 + r0 + (l >> 2)) * 512 + k0 + (l & 3) * 8,
                            &As[r0][0]);
            }
        } else if (INK == 0) {
            const float* X = (const float*)Xv;
            #pragma unroll
            for (int i = 0; i < 2; ++i) {
                int v   = t + 256 * i;
                int row = v >> 2;
                int c8  = (v & 3) * 8;
                const float* xp = X + (size_t)(m0 + row) * 512 + k0 + c8;
                float4v x0 = *(const float4v*)xp;
                float4v x1 = *(const float4v*)(xp + 4);
                ushort8 o;
                #pragma unroll
                for (int j = 0; j < 4; ++j) {
                    o[j]     = f2bf_fast(x0[j]);
                    o[j + 4] = f2bf_fast(x1[j]);
                }
                *(ushort8*)&As[row][c8] = o;
            }
        } else {  // INK == 2: sum of two bf16 partials
            const u16* P0 = (const u16*)X0v;
            const u16* P1 = (const u16*)X1v;
            #pragma unroll
            for (int i = 0; i < 2; ++i) {
                int v   = t + 256 * i;
                int row = v >> 2;
                int c8  = (v & 3) * 8;
                size_t gi = (size_t)(m0 + row) * 512 + k0 + c8;
                ushort8 a = *(const ushort8*)(P0 + gi);
                ushort8 b = *(const ushort8*)(P1 + gi);
                ushort8 o;
                #pragma unroll
                for (int j = 0; j < 8; ++j) o[j] = f2bf(bf2f(a[j]) + bf2f(b[j]));
                *(ushort8*)&As[row][c8] = o;
            }
        }

        // ---- stage B tile (W, bf16 via gload) ----
        if (WB16) {
            const u16* Wb = (const u16*)Wv;
            #pragma unroll
            for (int i = 0; i < 2; ++i) {
                int r0 = w * 32 + i * 16;
                gload_lds16(Wb + (size_t)(e0 + r0 + (l >> 2)) * 512 + k0 + (l & 3) * 8,
                            &Bs[r0][0]);
            }
        } else {
            const float* W = (const float*)Wv;
            #pragma unroll
            for (int i = 0; i < 2; ++i) {
                int v   = t + 256 * i;
                int row = v >> 2;
                int c8  = (v & 3) * 8;
                const float* wp = W + (size_t)(e0 + row) * 512 + k0 + c8;
                float4v w0 = *(const float4v*)wp;
                float4v w1 = *(const float4v*)(wp + 4);
                ushort8 o;
                #pragma unroll
                for (int j = 0; j < 4; ++j) {
                    o[j]     = f2bf_fast(w0[j]);
                    o[j + 4] = f2bf_fast(w1[j]);
                }
                *(ushort8*)&Bs[row][c8] = o;
            }
        }
        __syncthreads();

        short8 af[4], bfr[4];
        #pragma unroll
        for (int i = 0; i < 4; ++i)
            af[i] = *(const short8*)&As[wr + i * 16 + lane16][quad * 8];
        #pragma unroll
        for (int j = 0; j < 4; ++j)
            bfr[j] = *(const short8*)&Bs[wc + j * 16 + lane16][quad * 8];
        #pragma unroll
        for (int i = 0; i < 4; ++i)
            #pragma unroll
            for (int j = 0; j < 4; ++j)
                acc[i][j] = __builtin_amdgcn_mfma_f32_16x16x32_bf16(
                    af[i], bfr[j], acc[i][j], 0, 0, 0);
    }

    float bj[4];
    #pragma unroll
    for (int j = 0; j < 4; ++j) bj[j] = bias[e0 + wc + j * 16 + lane16];

    if (OUTB16) {
        if (z == 2) {   // transposed store: Vpt[b][e][n]
            u16* C = (u16*)C0v + 2 * (size_t)M * D_;
            #pragma unroll
            for (int i = 0; i < 4; ++i) {
                int mrow = m0 + wr + i * 16 + quad * 4;
                int bb = mrow >> 11, nb = mrow & (N_ - 1);
                #pragma unroll
                for (int j = 0; j < 4; ++j) {
                    int e = e0 + wc + j * 16 + lane16;
                    us4 o;
                    #pragma unroll
                    for (int r = 0; r < 4; ++r) o[r] = f2bf(acc[i][j][r] + bj[j]);
                    *(us4*)(C + (size_t)(bb * D_ + e) * N_ + nb) = o;
                }
            }
        } else {
            u16* C = (u16*)C0v + (size_t)z * (size_t)M * D_;
            #pragma unroll
            for (int i = 0; i < 4; ++i)
                #pragma unroll
                for (int j = 0; j < 4; ++j) {
                    int e = e0 + wc + j * 16 + lane16;
                    #pragma unroll
                    for (int r = 0; r < 4; ++r) {
                        int mrow = m0 + wr + i * 16 + quad * 4 + r;
                        C[(size_t)mrow * D_ + e] = f2bf(acc[i][j][r] + bj[j]);
                    }
                }
        }
    } else {
        float* C = (float*)C0v;
        #pragma unroll
        for (int i = 0; i < 4; ++i)
            #pragma unroll
            for (int j = 0; j < 4; ++j) {
                int e = e0 + wc + j * 16 + lane16;
                #pragma unroll
                for (int r = 0; r < 4; ++r) {
                    int mrow = m0 + wr + i * 16 + quad * 4 + r;
                    C[(size_t)mrow * D_ + e] = acc[i][j][r] + bj[j];
                }
            }
    }
}

// ---------------------------------------------------------------------------
// attn v7: 1024 thr = 16 waves (4/SIMD). Wave w -> ns=w>>2 (16 n-rows),
// ms=(w>>1)&1 (16-m half), hs=w&1 (heads hs*4..hs*4+3).
// Per chunk c (3 barriers, counted vmcnt):
//   1. VM(2): drain own V-reg loads(c)      [Kg(c+1) stays in flight]
//   2. commit vreg -> Vs
//   3. QK(c): 4 heads x own 16-m half (8 MFMA) from Ks[c&1]
//   4. e=exp(s/8); psum over own 4 heads -> Sx[ns][ms][n][m][hs]
//   5. issue V-reg loads(c+1)
//   6. LGKM0; BAR   (Sx + Vs visible; VMEM in flight)
//   7. inv = rcp(psum + Sx[...][hs^1]); write own 4 heads' P -> Ps
//   8. issue Kg(c+2) -> Ks[c&1]             [all waves past QK(c)]
//   9. LGKM0; BAR   (Ps visible)
//  10. PV: 8 heads x own d-tile dt=ms*2+hs (8 MFMA); pf from Ps, vf from Vs
//  11. VM(4): drain own Kg(c+1); BAR
// Hazard walk: every LDS buffer's writes are barrier-separated from all
// cross-wave reads; each wave drains its OWN gloads before the barrier
// preceding the cross-wave read (m218 pattern).
// LDS = 66,560(K) + 36,864(V) + 36,864(P) + 16,384(Sx) = 156,672 B.
// grid 256, flat&7 = (b,z) XCD pin. Qp,Kp: [b][n][d]. Vpt: [b][d][n].
// ---------------------------------------------------------------------------
__global__ __launch_bounds__(1024, 4) void attn_mfma7(
    const u16* __restrict__ Qp, const u16* __restrict__ Kp,
    const u16* __restrict__ Vpt, u16* __restrict__ A0)
{
    __shared__ u16 Ks[2][32][520];        // 66,560 B double-buffered K
    __shared__ u16 Vs[512][36];           // 36,864 B
    __shared__ u16 Ps[4][8][16][36];      // 36,864 B
    __shared__ float Sx[4][2][16][16][2]; // 16,384 B partial exp-sums

    const int t = threadIdx.x;
    const int w = t >> 6, l = t & 63;
    const int lane16 = l & 15, quad = l >> 4;
    const int ns = w >> 2, ms = (w >> 1) & 1, hs = w & 1;

    const int flat = blockIdx.x;
    const int xcd  = flat & 7;
    const int b = xcd >> 1;            // (b, z) pinned to one XCD
    const int z = xcd & 1;
    const int n0 = (flat >> 3) * 64 + ns * 16;
    const int seg  = N_ / 2;
    const int mbeg = z * seg;
    u16* A = A0 + (size_t)z * ((size_t)B_ * N_ * D_);

    const u16* Kb = Kp + (size_t)b * N_ * D_;
    // V staging: thread t covers rows d = {t>>2, 256 + t>>2}, part = t&3
    const int vd = t >> 2, vpart = (t & 3) * 8;
    const u16* Vsrc = Vpt + ((size_t)(b * D_ + vd)) * N_ + vpart;
    const int dt = ms * 2 + hs;        // owned d-tile for PV

    // Q fragments: own 4 heads x k=64 (32 VGPRs)
    short8 qfrag[4][2];
    {
        const u16* qb = Qp + ((size_t)(b * N_ + n0 + lane16) * D_ + quad * 8);
        #pragma unroll
        for (int hh = 0; hh < 4; ++hh)
            #pragma unroll
            for (int dc = 0; dc < 2; ++dc)
                qfrag[hh][dc] = *(const short8*)(qb + (hs * 4 + hh) * 64 + dc * 32);
    }

    float4v aacc[8];                   // 8 heads x own d-tile (32 VGPRs)
    #pragma unroll
    for (int h = 0; h < 8; ++h) aacc[h] = (float4v){0.f, 0.f, 0.f, 0.f};

    ushort8 vreg[2];                   // V prefetch registers (8 VGPRs)
    const int nch = seg / 32;          // 32 chunks

    // ---- prologue: Kg(0), Vl(0), Kg(1); drain Kg(0); barrier ----
    #pragma unroll
    for (int i = 0; i < 2; ++i)
        gload_lds16(Kb + (size_t)(mbeg + w * 2 + i) * D_ + l * 8,
                    &Ks[0][w * 2 + i][0]);
    #pragma unroll
    for (int i = 0; i < 2; ++i)
        vreg[i] = *(const ushort8*)(Vsrc + (size_t)(i * 256) * N_ + mbeg);
    #pragma unroll
    for (int i = 0; i < 2; ++i)
        gload_lds16(Kb + (size_t)(mbeg + 32 + w * 2 + i) * D_ + l * 8,
                    &Ks[1][w * 2 + i][0]);
    WAIT_VM(4);            // drain own Kg(0); Vl(0)+Kg(1) in flight
    BARRIER;

    for (int c = 0; c < nch; ++c) {
        const int cur = c & 1;
        const int mc  = mbeg + c * 32;

        // ---- 1: drain own V-reg loads(c) ----
        if (c + 1 < nch) { WAIT_VM(2); } else { WAIT_VM(0); }

        // ---- 2: commit V(c) to Vs ----
        #pragma unroll
        for (int i = 0; i < 2; ++i)
            *(ushort8*)&Vs[i * 256 + vd][vpart] = vreg[i];

        // ---- 3: QK^T (own 4 heads, own 16-m half) ----
        float4v sacc[4];
        #pragma unroll
        for (int hh = 0; hh < 4; ++hh) sacc[hh] = (float4v){0.f, 0.f, 0.f, 0.f};
        __builtin_amdgcn_s_setprio(1);
        #pragma unroll
        for (int hh = 0; hh < 4; ++hh)
            #pragma unroll
            for (int dc = 0; dc < 2; ++dc) {
                short8 kf = *(const short8*)
                    &Ks[cur][ms * 16 + lane16][(hs * 4 + hh) * 64 + dc * 32 + quad * 8];
                sacc[hh] = __builtin_amdgcn_mfma_f32_16x16x32_bf16(
                    qfrag[hh][dc], kf, sacc[hh], 0, 0, 0);
            }
        __builtin_amdgcn_s_setprio(0);

        // ---- 4: e = exp(s/8); partial sums -> Sx ----
        float psum[4];
        #pragma unroll
        for (int r = 0; r < 4; ++r) {
            float s = 0.f;
            #pragma unroll
            for (int hh = 0; hh < 4; ++hh) {
                sacc[hh][r] = __expf(sacc[hh][r] * 0.125f);   // 1/sqrt(64)
                s += sacc[hh][r];
            }
            psum[r] = s;
            Sx[ns][ms][quad * 4 + r][lane16][hs] = s;
        }

        // ---- 5: prefetch V(c+1) into registers ----
        if (c + 1 < nch) {
            #pragma unroll
            for (int i = 0; i < 2; ++i)
                vreg[i] = *(const ushort8*)
                    (Vsrc + (size_t)(i * 256) * N_ + mc + 32);
        }

        // ---- 6: Sx + Vs visible; VMEM stays in flight ----
        WAIT_LGKM0;
        BARRIER;

        // ---- 7: full-sum normalize; write own 4 heads' P -> Ps ----
        #pragma unroll
        for (int r = 0; r < 4; ++r) {
            float other = Sx[ns][ms][quad * 4 + r][lane16][hs ^ 1];
            float inv = __builtin_amdgcn_rcpf(psum[r] + other);
            #pragma unroll
            for (int hh = 0; hh < 4; ++hh)
                Ps[ns][hs * 4 + hh][quad * 4 + r][ms * 16 + lane16] =
                    f2bf_fast(sacc[hh][r] * inv);
        }

        // ---- 8: prefetch K(c+2) into the Ks buffer QK(c) just freed ----
        if (c + 2 < nch) {
            #pragma unroll
            for (int i = 0; i < 2; ++i)
                gload_lds16(Kb + (size_t)(mc + 64 + w * 2 + i) * D_ + l * 8,
                            &Ks[cur][w * 2 + i][0]);
        }

        // ---- 9: Ps visible ----
        WAIT_LGKM0;
        BARRIER;

        // ---- 10: PV, full k=32; 8 heads x own d-tile ----
        __builtin_amdgcn_s_setprio(1);
        #pragma unroll
        for (int h = 0; h < 8; ++h) {
            short8 pf = *(const short8*)&Ps[ns][h][lane16][quad * 8];
            short8 vf = *(const short8*)
                &Vs[h * 64 + dt * 16 + lane16][quad * 8];
            aacc[h] = __builtin_amdgcn_mfma_f32_16x16x32_bf16(
                pf, vf, aacc[h], 0, 0, 0);
        }
        __builtin_amdgcn_s_setprio(0);

        // ---- 11: drain own Kg(c+1) before barrier -> QK(c+1) safe ----
        if (c + 1 < nch) {
            if (c + 2 < nch) { WAIT_VM(4); } else { WAIT_VM(2); }
            BARRIER;
        }
    }

    // ---- store partial A (bf16), own d-tile columns only ----
    #pragma unroll
    for (int h = 0; h < 8; ++h)
        #pragma unroll
        for (int r = 0; r < 4; ++r) {
            const int n = n0 + quad * 4 + r;
            const int d = h * 64 + dt * 16 + lane16;
            A[(size_t)(b * N_ + n) * D_ + d] = f2bf(aacc[h][r]);
        }
}

// ---------------------------------------------------------------------------
extern "C" void kernel_launch(void* const* d_in, const int* in_sizes, int n_in,
                              void* d_out, int out_size, void* d_ws, size_t ws_size,
                              hipStream_t stream)
{
    const float* Q  = (const float*)d_in[0];
    const float* K  = (const float*)d_in[1];
    const float* V  = (const float*)d_in[2];
    const float* Wq = (const float*)d_in[3];
    const float* bq = (const float*)d_in[4];
    const float* Wo = (const float*)d_in[5];
    const float* bo = (const float*)d_in[6];
    float* out = (float*)d_out;
    u16*   ws  = (u16*)d_ws;

    const size_t NBD = (size_t)B_ * N_ * D_;   // 4,194,304
    const int M = B_ * N_;                     // 8192

    const size_t need6 = (6 * NBD + 2 * (size_t)D_ * D_) * sizeof(u16); // 51.4 MB

    if (ws_size >= need6) {
        // Path A: bf16-ify inputs once; proj1 all-gload. Slab reuse:
        // S0=Qb->Pa, S1=Kb->Pb, S2=Vb, S3=Qp, S4=Kp, S5=Vpt, then Wb.
        u16* S0 = ws;
        u16* S1 = ws + NBD;
        u16* S2 = ws + 2 * NBD;
        u16* S3 = ws + 3 * NBD;
        u16* Wb = ws + 6 * NBD;            // [Wqb | Wob]

        cvt4<<<dim3((unsigned)(NBD / 2048), 4), dim3(256), 0, stream>>>(
            Q, K, V, Wq, Wo, S0, Wb);

        proj_mfma<1, true, true, 3><<<dim3(768), dim3(256), 0, stream>>>(
            S0, S1, S2, Wb, bq, S3, M);    // -> Qp(S3), Kp(S4), Vpt(S5)

        attn_mfma7<<<dim3(256), dim3(1024), 0, stream>>>(
            S3, S3 + NBD, S3 + 2 * NBD, S0);   // partials -> S0, S1

        proj_mfma<2, true, false, 1><<<dim3(256), dim3(256), 0, stream>>>(
            S0, S1, S1, Wb + (size_t)D_ * D_, bo, out, M);
    } else {
        // Path B (proven 43.0 MB): fp32-X staging in proj1.
        u16* Qp  = ws;
        u16* Kp  = ws + NBD;
        u16* Vpt = ws + 2 * NBD;
        u16* Pa  = ws + 3 * NBD;
        u16* Pb  = ws + 4 * NBD;
        u16* Wb  = ws + 5 * NBD;

        wconv<<<dim3(128, 2), dim3(256), 0, stream>>>(Wq, Wo, Wb);

        proj_mfma<0, true, true, 3><<<dim3(768), dim3(256), 0, stream>>>(
            Q, K, V, Wb, bq, Qp, M);

        attn_mfma7<<<dim3(256), dim3(1024), 0, stream>>>(Qp, Kp, Vpt, Pa);

        proj_mfma<2, true, false, 1><<<dim3(256), dim3(256), 0, stream>>>(
            Pa, Pb, Pb, Wb + (size_t)D_ * D_, bo, out, M);
    }
}

// Round 5
// 236.628 us; speedup vs baseline: 1.0307x; 1.0307x over previous
//
#include <hip/hip_runtime.h>
#include <hip/hip_bf16.h>

// B,N,D,H = 4,2048,512,8 (DK=64). fp32 I/O; bf16 intermediates in ws.
// v8: attn reverted to v6 (104us proven; v7's 4-waves/SIMD raised LDS
// traffic and regressed - attn is LDS-pipe-bound, not latency-bound).
// proj2 retiled 128x64 -> 512 blocks = 2 blocks/CU (was 256 = 1/CU with
// fully exposed barrier drains - same 1-block/CU exposure that made attn
// v3 slow). Round also disambiguates the stable ~135us non-attn residual.
#define B_  4
#define N_  2048
#define D_  512
#define H_  8

typedef unsigned short u16;
typedef __attribute__((ext_vector_type(8))) unsigned short ushort8;
typedef __attribute__((ext_vector_type(4))) unsigned short us4;
typedef __attribute__((ext_vector_type(8))) short short8;
typedef __attribute__((ext_vector_type(4))) float float4v;

__device__ __forceinline__ float bf2f(u16 u) {
    union { unsigned int i; float f; } v;
    v.i = ((unsigned int)u) << 16;
    return v.f;
}
__device__ __forceinline__ u16 f2bf(float f) {          // RNE
    union { float f; unsigned int i; } v;
    v.f = f;
    unsigned int r = v.i + 0x7FFFu + ((v.i >> 16) & 1u);
    return (u16)(r >> 16);
}
__device__ __forceinline__ u16 f2bf_fast(float f) {     // round-half-up
    union { float f; unsigned int i; } v;
    v.f = f;
    return (u16)((v.i + 0x8000u) >> 16);
}

// async global->LDS, 16B/lane, dest = wave-uniform base + lane*16 (m104 rule)
__device__ __forceinline__ void gload_lds16(const void* g, void* l) {
    __builtin_amdgcn_global_load_lds(
        (const __attribute__((address_space(1))) unsigned int*)g,
        (__attribute__((address_space(3))) unsigned int*)l, 16, 0, 0);
}

#define WAIT_VM(N) do { \
    asm volatile("s_waitcnt vmcnt(" #N ")" ::: "memory"); \
    __builtin_amdgcn_sched_barrier(0); } while (0)
#define WAIT_LGKM0 do { \
    asm volatile("s_waitcnt lgkmcnt(0)" ::: "memory"); \
    __builtin_amdgcn_sched_barrier(0); } while (0)
#define BARRIER do { \
    __builtin_amdgcn_s_barrier(); \
    __builtin_amdgcn_sched_barrier(0); } while (0)

// ---------------------------------------------------------------------------
// wconv: Wq,Wo fp32 -> bf16, out = [Wqb | Wob]. grid (128, 2) x 256.
// (Path B only; Path A uses fused cvt4.)
// ---------------------------------------------------------------------------
__global__ __launch_bounds__(256) void wconv(
    const float* __restrict__ Wq, const float* __restrict__ Wo,
    u16* __restrict__ out)
{
    const int idx = (blockIdx.x * 256 + threadIdx.x) * 8;
    const float* src = blockIdx.y ? Wo : Wq;
    u16* dst = out + (size_t)blockIdx.y * (D_ * D_) + idx;
    float4v a = *(const float4v*)(src + idx);
    float4v b = *(const float4v*)(src + idx + 4);
    ushort8 o;
    #pragma unroll
    for (int j = 0; j < 4; ++j) { o[j] = f2bf(a[j]); o[j + 4] = f2bf(b[j]); }
    *(ushort8*)dst = o;
}

// ---------------------------------------------------------------------------
// cvt4: Q,K,V fp32 -> bf16 slabs, + Wq/Wo -> Wb fused (y==3 blocks).
// grid (NBD/2048, 4) x 256.
// ---------------------------------------------------------------------------
__global__ __launch_bounds__(256) void cvt4(
    const float* __restrict__ Q, const float* __restrict__ K,
    const float* __restrict__ V, const float* __restrict__ Wq,
    const float* __restrict__ Wo, u16* __restrict__ out,
    u16* __restrict__ wb)
{
    const int y = blockIdx.y;
    if (y == 3) {                      // weight conversion: 2*D*D elems
        if (blockIdx.x >= 256) return; // 256 blocks * 2048 = 524,288
        const int idx = (blockIdx.x * 256 + threadIdx.x) * 8;
        const bool hi = idx >= D_ * D_;     // no straddle: 2048 | D*D
        const float* src = hi ? Wo : Wq;
        const int off = hi ? idx - D_ * D_ : idx;
        float4v a = *(const float4v*)(src + off);
        float4v b = *(const float4v*)(src + off + 4);
        ushort8 o;
        #pragma unroll
        for (int j = 0; j < 4; ++j) { o[j] = f2bf(a[j]); o[j + 4] = f2bf(b[j]); }
        *(ushort8*)(wb + idx) = o;
        return;
    }
    const size_t NBD = (size_t)B_ * N_ * D_;
    const float* src = (y == 0) ? Q : ((y == 1) ? K : V);
    u16* dst = out + (size_t)y * NBD;
    size_t idx = ((size_t)blockIdx.x * 256 + threadIdx.x) * 8;
    float4v a = *(const float4v*)(src + idx);
    float4v b = *(const float4v*)(src + idx + 4);
    ushort8 o;
    #pragma unroll
    for (int j = 0; j < 4; ++j) { o[j] = f2bf(a[j]); o[j + 4] = f2bf(b[j]); }
    *(ushort8*)(dst + idx) = o;
}

// ---------------------------------------------------------------------------
// MFMA GEMM: C[M,512] = X @ W^T + bias.  1D grid, XCD swizzle: the 4 e-tiles
// of one (z,m) X-panel land on one XCD (flat&7 selects (z,m) low bits).
// INK: 0 = X fp32 (VALU cvt), 1 = X bf16 (gload), 2 = X0+X1 bf16 partials.
// WB16: W bf16 via gload. OUTB16: C bf16 (z==2 -> transposed Vpt[b][e][n]).
// 128x128 tile, 4 waves x 4x4 MFMA 16x16x32, BK=32.
// ---------------------------------------------------------------------------
template <int INK, bool WB16, bool OUTB16, int NZ>
__global__ __launch_bounds__(256) void proj_mfma(
    const void* __restrict__ X0v, const void* __restrict__ X1v,
    const void* __restrict__ X2v, const void* __restrict__ Wv,
    const float* __restrict__ bias, void* __restrict__ C0v, int M)
{
    __shared__ u16 As[128][32];
    __shared__ u16 Bs[128][32];

    const int t = threadIdx.x;
    // swizzle decode: flat = xcd + 8*(e + 4*g), zm = xcd + 8*g
    const int flat = blockIdx.x;
    const int xcd = flat & 7, rr = flat >> 3;
    const int eb = rr & 3, g = rr >> 2;
    const int zm = xcd + 8 * g;          // 0 .. 64*NZ-1
    const int z  = zm >> 6;
    const int e0 = eb * 128;
    const int m0 = (zm & 63) * 128;

    const void* Xv = (z == 0) ? X0v : ((z == 1) ? X1v : X2v);
    const int w = t >> 6, l = t & 63;
    const int lane16 = l & 15, quad = l >> 4;
    const int wr = (w >> 1) * 64;
    const int wc = (w & 1) * 64;

    float4v acc[4][4];
    #pragma unroll
    for (int i = 0; i < 4; ++i)
        #pragma unroll
        for (int j = 0; j < 4; ++j)
            acc[i][j] = (float4v){0.f, 0.f, 0.f, 0.f};

    for (int k0 = 0; k0 < 512; k0 += 32) {
        __syncthreads();

        // ---- stage A tile ----
        if (INK == 1) {
            const u16* X = (const u16*)Xv;
            #pragma unroll
            for (int i = 0; i < 2; ++i) {
                int r0 = w * 32 + i * 16;
                gload_lds16(X + (size_t)(m0 + r0 + (l >> 2)) * 512 + k0 + (l & 3) * 8,
                            &As[r0][0]);
            }
        } else if (INK == 0) {
            const float* X = (const float*)Xv;
            #pragma unroll
            for (int i = 0; i < 2; ++i) {
                int v   = t + 256 * i;
                int row = v >> 2;
                int c8  = (v & 3) * 8;
                const float* xp = X + (size_t)(m0 + row) * 512 + k0 + c8;
                float4v x0 = *(const float4v*)xp;
                float4v x1 = *(const float4v*)(xp + 4);
                ushort8 o;
                #pragma unroll
                for (int j = 0; j < 4; ++j) {
                    o[j]     = f2bf_fast(x0[j]);
                    o[j + 4] = f2bf_fast(x1[j]);
                }
                *(ushort8*)&As[row][c8] = o;
            }
        } else {  // INK == 2: sum of two bf16 partials
            const u16* P0 = (const u16*)X0v;
            const u16* P1 = (const u16*)X1v;
            #pragma unroll
            for (int i = 0; i < 2; ++i) {
                int v   = t + 256 * i;
                int row = v >> 2;
                int c8  = (v & 3) * 8;
                size_t gi = (size_t)(m0 + row) * 512 + k0 + c8;
                ushort8 a = *(const ushort8*)(P0 + gi);
                ushort8 b = *(const ushort8*)(P1 + gi);
                ushort8 o;
                #pragma unroll
                for (int j = 0; j < 8; ++j) o[j] = f2bf(bf2f(a[j]) + bf2f(b[j]));
                *(ushort8*)&As[row][c8] = o;
            }
        }

        // ---- stage B tile (W, bf16 via gload) ----
        if (WB16) {
            const u16* Wb = (const u16*)Wv;
            #pragma unroll
            for (int i = 0; i < 2; ++i) {
                int r0 = w * 32 + i * 16;
                gload_lds16(Wb + (size_t)(e0 + r0 + (l >> 2)) * 512 + k0 + (l & 3) * 8,
                            &Bs[r0][0]);
            }
        } else {
            const float* W = (const float*)Wv;
            #pragma unroll
            for (int i = 0; i < 2; ++i) {
                int v   = t + 256 * i;
                int row = v >> 2;
                int c8  = (v & 3) * 8;
                const float* wp = W + (size_t)(e0 + row) * 512 + k0 + c8;
                float4v w0 = *(const float4v*)wp;
                float4v w1 = *(const float4v*)(wp + 4);
                ushort8 o;
                #pragma unroll
                for (int j = 0; j < 4; ++j) {
                    o[j]     = f2bf_fast(w0[j]);
                    o[j + 4] = f2bf_fast(w1[j]);
                }
                *(ushort8*)&Bs[row][c8] = o;
            }
        }
        __syncthreads();

        short8 af[4], bfr[4];
        #pragma unroll
        for (int i = 0; i < 4; ++i)
            af[i] = *(const short8*)&As[wr + i * 16 + lane16][quad * 8];
        #pragma unroll
        for (int j = 0; j < 4; ++j)
            bfr[j] = *(const short8*)&Bs[wc + j * 16 + lane16][quad * 8];
        #pragma unroll
        for (int i = 0; i < 4; ++i)
            #pragma unroll
            for (int j = 0; j < 4; ++j)
                acc[i][j] = __builtin_amdgcn_mfma_f32_16x16x32_bf16(
                    af[i], bfr[j], acc[i][j], 0, 0, 0);
    }

    float bj[4];
    #pragma unroll
    for (int j = 0; j < 4; ++j) bj[j] = bias[e0 + wc + j * 16 + lane16];

    if (OUTB16) {
        if (z == 2) {   // transposed store: Vpt[b][e][n]
            u16* C = (u16*)C0v + 2 * (size_t)M * D_;
            #pragma unroll
            for (int i = 0; i < 4; ++i) {
                int mrow = m0 + wr + i * 16 + quad * 4;
                int bb = mrow >> 11, nb = mrow & (N_ - 1);
                #pragma unroll
                for (int j = 0; j < 4; ++j) {
                    int e = e0 + wc + j * 16 + lane16;
                    us4 o;
                    #pragma unroll
                    for (int r = 0; r < 4; ++r) o[r] = f2bf(acc[i][j][r] + bj[j]);
                    *(us4*)(C + (size_t)(bb * D_ + e) * N_ + nb) = o;
                }
            }
        } else {
            u16* C = (u16*)C0v + (size_t)z * (size_t)M * D_;
            #pragma unroll
            for (int i = 0; i < 4; ++i)
                #pragma unroll
                for (int j = 0; j < 4; ++j) {
                    int e = e0 + wc + j * 16 + lane16;
                    #pragma unroll
                    for (int r = 0; r < 4; ++r) {
                        int mrow = m0 + wr + i * 16 + quad * 4 + r;
                        C[(size_t)mrow * D_ + e] = f2bf(acc[i][j][r] + bj[j]);
                    }
                }
        }
    } else {
        float* C = (float*)C0v;
        #pragma unroll
        for (int i = 0; i < 4; ++i)
            #pragma unroll
            for (int j = 0; j < 4; ++j) {
                int e = e0 + wc + j * 16 + lane16;
                #pragma unroll
                for (int r = 0; r < 4; ++r) {
                    int mrow = m0 + wr + i * 16 + quad * 4 + r;
                    C[(size_t)mrow * D_ + e] = acc[i][j][r] + bj[j];
                }
            }
    }
}

// ---------------------------------------------------------------------------
// proj2_mfma: out[8192,512] = (P0+P1) @ Wo^T + bo, fp32 out.
// 128x64 tile -> 512 blocks = 2 blocks/CU (cross-block overlap hides the
// barrier drains that a 1-block/CU dispatch fully exposes).
// 4 waves, each owns 64x32 (acc 4x2), 8 MFMA/K-step, BK=32, LDS 12 KB.
// Swizzle: flat&7 = xcd; m-tile = xcd + 8*(rr>>3) so the 8 e-tiles of one
// m-panel share an XCD (A-panel L2 reuse). W fits L2 everywhere (512 KB).
// ---------------------------------------------------------------------------
__global__ __launch_bounds__(256) void proj2_mfma(
    const u16* __restrict__ P0, const u16* __restrict__ P1,
    const u16* __restrict__ Wv, const float* __restrict__ bias,
    float* __restrict__ C)
{
    __shared__ u16 As[128][32];
    __shared__ u16 Bs[64][32];

    const int t = threadIdx.x;
    const int flat = blockIdx.x;
    const int xcd = flat & 7, rr = flat >> 3;
    const int eb = rr & 7, g = rr >> 3;
    const int m0 = (xcd + 8 * g) * 128;
    const int e0 = eb * 64;

    const int w = t >> 6, l = t & 63;
    const int lane16 = l & 15, quad = l >> 4;
    const int wr = (w >> 1) * 64;
    const int wc = (w & 1) * 32;

    float4v acc[4][2];
    #pragma unroll
    for (int i = 0; i < 4; ++i)
        #pragma unroll
        for (int j = 0; j < 2; ++j)
            acc[i][j] = (float4v){0.f, 0.f, 0.f, 0.f};

    for (int k0 = 0; k0 < 512; k0 += 32) {
        __syncthreads();

        // ---- stage A = P0 + P1 (bf16 partial sums) ----
        #pragma unroll
        for (int i = 0; i < 2; ++i) {
            int v   = t + 256 * i;
            int row = v >> 2;
            int c8  = (v & 3) * 8;
            size_t gi = (size_t)(m0 + row) * 512 + k0 + c8;
            ushort8 a = *(const ushort8*)(P0 + gi);
            ushort8 b = *(const ushort8*)(P1 + gi);
            ushort8 o;
            #pragma unroll
            for (int j = 0; j < 8; ++j) o[j] = f2bf(bf2f(a[j]) + bf2f(b[j]));
            *(ushort8*)&As[row][c8] = o;
        }

        // ---- stage B tile (W, bf16 via gload; 64 rows = 1 gload/wave) ----
        gload_lds16(Wv + (size_t)(e0 + w * 16 + (l >> 2)) * 512 + k0 + (l & 3) * 8,
                    &Bs[w * 16][0]);
        __syncthreads();

        short8 af[4], bfr[2];
        #pragma unroll
        for (int i = 0; i < 4; ++i)
            af[i] = *(const short8*)&As[wr + i * 16 + lane16][quad * 8];
        #pragma unroll
        for (int j = 0; j < 2; ++j)
            bfr[j] = *(const short8*)&Bs[wc + j * 16 + lane16][quad * 8];
        #pragma unroll
        for (int i = 0; i < 4; ++i)
            #pragma unroll
            for (int j = 0; j < 2; ++j)
                acc[i][j] = __builtin_amdgcn_mfma_f32_16x16x32_bf16(
                    af[i], bfr[j], acc[i][j], 0, 0, 0);
    }

    float bj[2];
    #pragma unroll
    for (int j = 0; j < 2; ++j) bj[j] = bias[e0 + wc + j * 16 + lane16];

    #pragma unroll
    for (int i = 0; i < 4; ++i)
        #pragma unroll
        for (int j = 0; j < 2; ++j) {
            int e = e0 + wc + j * 16 + lane16;
            #pragma unroll
            for (int r = 0; r < 4; ++r) {
                int mrow = m0 + wr + i * 16 + quad * 4 + r;
                C[(size_t)mrow * D_ + e] = acc[i][j][r] + bj[j];
            }
        }
}

// ---------------------------------------------------------------------------
// attn v6 (reverted, proven 104us): 512 thr = 8 waves (ns owns 16 n-rows,
// ms splits the 32-m chunk). Counted-vmcnt pipeline, per chunk c:
//   VM(4) drain V-reg loads(c); commit Vs; QK(c) from Ks[c&1]; register
//   heads-softmax -> Ps; issue V-reg loads(c+1); LGKM0+BAR; issue
//   Kg(c+2) -> Ks[c&1]; PV(c); VM(8) drain Kg(c+1); LGKM0+BAR.
// Vs/Ps stride 36 u16 (conflict-free). LDS 140,288 B. grid 256, flat&7=(b,z).
// ---------------------------------------------------------------------------
__global__ __launch_bounds__(512, 2) void attn_mfma6(
    const u16* __restrict__ Qp, const u16* __restrict__ Kp,
    const u16* __restrict__ Vpt, u16* __restrict__ A0)
{
    __shared__ u16 Ks[2][32][520];     // 66,560 B double-buffered K
    __shared__ u16 Vs[512][36];        // 36,864 B (stride-36: clean banks)
    __shared__ u16 Ps[4][8][16][36];   // 36,864 B pair-shared P per n-tile

    const int t = threadIdx.x;
    const int w = t >> 6, l = t & 63;
    const int lane16 = l & 15, quad = l >> 4;
    const int ns = w >> 1, ms = w & 1;

    const int flat = blockIdx.x;
    const int xcd  = flat & 7;
    const int b = xcd >> 1;            // (b, z) pinned to one XCD
    const int z = xcd & 1;
    const int n0 = (flat >> 3) * 64 + ns * 16;   // this wave-pair's 16 rows
    const int seg  = N_ / 2;
    const int mbeg = z * seg;
    u16* A = A0 + (size_t)z * ((size_t)B_ * N_ * D_);

    const u16* Kb = Kp + (size_t)b * N_ * D_;
    // V staging source: thread t covers (d = v>>2, part = v&3), v = i*512+t
    const int vd0 = t >> 2, vpart = (t & 3) * 8;
    const u16* Vsrc = Vpt + (size_t)(b * D_) * N_ + vpart;

    // Q fragments: 8 heads x k=64, A-operand layout, persistent (64 VGPRs)
    short8 qfrag[8][2];
    {
        const u16* qb = Qp + ((size_t)(b * N_ + n0 + lane16) * D_ + quad * 8);
        #pragma unroll
        for (int h = 0; h < 8; ++h)
            #pragma unroll
            for (int dc = 0; dc < 2; ++dc)
                qfrag[h][dc] = *(const short8*)(qb + h * 64 + dc * 32);
    }

    float4v aacc[8][2];                // 8 heads x 2 owned d-tiles (64 regs)
    #pragma unroll
    for (int h = 0; h < 8; ++h)
        #pragma unroll
        for (int dt = 0; dt < 2; ++dt)
            aacc[h][dt] = (float4v){0.f, 0.f, 0.f, 0.f};

    ushort8 vreg[4];                   // V prefetch registers (16 VGPRs)
    const int nch = seg / 32;          // 32 chunks

    // ---- prologue: Kg(0), Vl(0), Kg(1); drain Kg(0); barrier ----
    #pragma unroll
    for (int i = 0; i < 4; ++i)
        gload_lds16(Kb + (size_t)(mbeg + w * 4 + i) * D_ + l * 8,
                    &Ks[0][w * 4 + i][0]);
    #pragma unroll
    for (int i = 0; i < 4; ++i)
        vreg[i] = *(const ushort8*)(Vsrc + (size_t)(i * 128 + vd0) * N_ + mbeg);
    #pragma unroll
    for (int i = 0; i < 4; ++i)
        gload_lds16(Kb + (size_t)(mbeg + 32 + w * 4 + i) * D_ + l * 8,
                    &Ks[1][w * 4 + i][0]);
    WAIT_VM(8);            // drain Kg(0); Vl(0)+Kg(1) stay in flight
    BARRIER;               // all waves' Kg(0) landed

    for (int c = 0; c < nch; ++c) {
        const int cur = c & 1;
        const int mc  = mbeg + c * 32;

        // ---- 1: drain own V-reg loads(c) ----
        if (c < nch - 1) { WAIT_VM(4); } else { WAIT_VM(0); }

        // ---- 2: commit V(c) to Vs ----
        #pragma unroll
        for (int i = 0; i < 4; ++i)
            *(ushort8*)&Vs[i * 128 + vd0][vpart] = vreg[i];

        // ---- 3: QK^T (8 heads, own 16-m half) ----
        float4v sacc[8];
        #pragma unroll
        for (int h = 0; h < 8; ++h) sacc[h] = (float4v){0.f, 0.f, 0.f, 0.f};
        __builtin_amdgcn_s_setprio(1);
        #pragma unroll
        for (int h = 0; h < 8; ++h)
            #pragma unroll
            for (int dc = 0; dc < 2; ++dc) {
                short8 kf = *(const short8*)
                    &Ks[cur][ms * 16 + lane16][h * 64 + dc * 32 + quad * 8];
                sacc[h] = __builtin_amdgcn_mfma_f32_16x16x32_bf16(
                    qfrag[h][dc], kf, sacc[h], 0, 0, 0);
            }
        __builtin_amdgcn_s_setprio(0);

        // ---- 4: register heads-softmax -> Ps ----
        #pragma unroll
        for (int r = 0; r < 4; ++r) {
            float p[8]; float sum = 0.f;
            #pragma unroll
            for (int h = 0; h < 8; ++h) {
                p[h] = __expf(sacc[h][r] * 0.125f);   // 1/sqrt(64)
                sum += p[h];
            }
            float inv = __builtin_amdgcn_rcpf(sum);
            #pragma unroll
            for (int h = 0; h < 8; ++h)
                Ps[ns][h][quad * 4 + r][ms * 16 + lane16] = f2bf(p[h] * inv);
        }

        // ---- 5: prefetch V(c+1) into registers ----
        if (c + 1 < nch) {
            #pragma unroll
            for (int i = 0; i < 4; ++i)
                vreg[i] = *(const ushort8*)
                    (Vsrc + (size_t)(i * 128 + vd0) * N_ + mc + 32);
        }

        // ---- 6: Ps+Vs visible; VMEM prefetches stay in flight ----
        WAIT_LGKM0;
        BARRIER;

        // ---- 7: prefetch K(c+2) into the Ks buffer QK(c) just freed ----
        if (c + 2 < nch) {
            #pragma unroll
            for (int i = 0; i < 4; ++i)
                gload_lds16(Kb + (size_t)(mc + 64 + w * 4 + i) * D_ + l * 8,
                            &Ks[cur][w * 4 + i][0]);
        }

        // ---- 8: PV, full k=32; each wave owns d-tiles ms*2 + {0,1} ----
        __builtin_amdgcn_s_setprio(1);
        #pragma unroll
        for (int h = 0; h < 8; ++h) {
            short8 pf = *(const short8*)&Ps[ns][h][lane16][quad * 8];
            #pragma unroll
            for (int dt = 0; dt < 2; ++dt) {
                short8 vf = *(const short8*)
                    &Vs[h * 64 + (ms * 2 + dt) * 16 + lane16][quad * 8];
                aacc[h][dt] = __builtin_amdgcn_mfma_f32_16x16x32_bf16(
                    pf, vf, aacc[h][dt], 0, 0, 0);
            }
        }
        __builtin_amdgcn_s_setprio(0);

        // ---- 9: drain own Kg(c+1) before barrier -> QK(c+1) safe ----
        if (c < nch - 1) {
            if (c + 2 < nch) { WAIT_VM(8); } else { WAIT_VM(4); }
            WAIT_LGKM0;
            BARRIER;
        }
    }

    // ---- store partial A (bf16), own d-columns only ----
    #pragma unroll
    for (int h = 0; h < 8; ++h)
        #pragma unroll
        for (int dt = 0; dt < 2; ++dt)
            #pragma unroll
            for (int r = 0; r < 4; ++r) {
                const int n = n0 + quad * 4 + r;
                const int d = h * 64 + (ms * 2 + dt) * 16 + lane16;
                A[(size_t)(b * N_ + n) * D_ + d] = f2bf(aacc[h][dt][r]);
            }
}

// ---------------------------------------------------------------------------
extern "C" void kernel_launch(void* const* d_in, const int* in_sizes, int n_in,
                              void* d_out, int out_size, void* d_ws, size_t ws_size,
                              hipStream_t stream)
{
    const float* Q  = (const float*)d_in[0];
    const float* K  = (const float*)d_in[1];
    const float* V  = (const float*)d_in[2];
    const float* Wq = (const float*)d_in[3];
    const float* bq = (const float*)d_in[4];
    const float* Wo = (const float*)d_in[5];
    const float* bo = (const float*)d_in[6];
    float* out = (float*)d_out;
    u16*   ws  = (u16*)d_ws;

    const size_t NBD = (size_t)B_ * N_ * D_;   // 4,194,304
    const int M = B_ * N_;                     // 8192

    const size_t need6 = (6 * NBD + 2 * (size_t)D_ * D_) * sizeof(u16); // 51.4 MB

    if (ws_size >= need6) {
        // Path A: bf16-ify inputs once; proj1 all-gload. Slab reuse:
        // S0=Qb->Pa, S1=Kb->Pb, S2=Vb, S3=Qp, S4=Kp, S5=Vpt, then Wb.
        u16* S0 = ws;
        u16* S1 = ws + NBD;
        u16* S2 = ws + 2 * NBD;
        u16* S3 = ws + 3 * NBD;
        u16* Wb = ws + 6 * NBD;            // [Wqb | Wob]

        cvt4<<<dim3((unsigned)(NBD / 2048), 4), dim3(256), 0, stream>>>(
            Q, K, V, Wq, Wo, S0, Wb);

        proj_mfma<1, true, true, 3><<<dim3(768), dim3(256), 0, stream>>>(
            S0, S1, S2, Wb, bq, S3, M);    // -> Qp(S3), Kp(S4), Vpt(S5)

        attn_mfma6<<<dim3(256), dim3(512), 0, stream>>>(
            S3, S3 + NBD, S3 + 2 * NBD, S0);   // partials -> S0, S1

        proj2_mfma<<<dim3(512), dim3(256), 0, stream>>>(
            S0, S1, Wb + (size_t)D_ * D_, bo, out);
    } else {
        // Path B (proven 43.0 MB): fp32-X staging in proj1.
        u16* Qp  = ws;
        u16* Kp  = ws + NBD;
        u16* Vpt = ws + 2 * NBD;
        u16* Pa  = ws + 3 * NBD;
        u16* Pb  = ws + 4 * NBD;
        u16* Wb  = ws + 5 * NBD;

        wconv<<<dim3(128, 2), dim3(256), 0, stream>>>(Wq, Wo, Wb);

        proj_mfma<0, true, true, 3><<<dim3(768), dim3(256), 0, stream>>>(
            Q, K, V, Wb, bq, Qp, M);

        attn_mfma6<<<dim3(256), dim3(512), 0, stream>>>(Qp, Kp, Vpt, Pa);

        proj2_mfma<<<dim3(512), dim3(256), 0, stream>>>(
            Pa, Pb, Wb + (size_t)D_ * D_, bo, out);
    }
}